// Round 3
// baseline (7112.091 us; speedup 1.0000x reference)
//
#include <hip/hip_runtime.h>
#include <stdint.h>

// LSTM forward, B=128 T=512 F=256 H=512, Keras gate order i,f,g,o.
//  kernel lstm_xz : xz[B*T,2048] = x @ kernel + bias  (split-bf16 MFMA, fp16 output in ws)
//  kernel lstm_rec: persistent scan. 8 row groups (16 rows) x 64 col-blocks (8 h-cols).
//    R2: tag-broadcast barrier (no atomic RMW chain, no cnt->gen double hop) +
//    wave specialization: wave0 = gates/stores only; waves1-3 = poll + h staging;
//    wave1 = xz prefetch into LDS ping-pong (HBM latency off wave0's ack path).
//    All cross-block traffic is device-scope RELAXED (sc1) — no L2 inv/wbl2.
// ws layout: [0, 256MB) xz fp16 | hbuf 2x128x512 bf16 (256KB) | tags 2KB

#define Bb 128
#define Tt 512
#define Ff 256
#define Hh 512
#define G4 2048

typedef __attribute__((ext_vector_type(8))) short short8;
typedef __attribute__((ext_vector_type(4))) float floatx4;

__device__ __forceinline__ unsigned short f2bf(float f) {
    unsigned u = __float_as_uint(f);
    return (unsigned short)((u + 0x7FFFu + ((u >> 16) & 1u)) >> 16);
}
__device__ __forceinline__ float bf2f(unsigned short h) {
    return __uint_as_float(((unsigned)h) << 16);
}
__device__ __forceinline__ float sigm(float x) { return 1.f / (1.f + __expf(-x)); }
__device__ __forceinline__ float tanh_f(float x) {
    float e = __expf(-2.f * fabsf(x));
    return copysignf((1.f - e) / (1.f + e), x);
}

// ---------------------------------------------------------------------------
// Kernel A: xz = x @ w + bias, stored fp16. Split-bf16 (x=hi+lo) for accuracy.
// 128x128 tile / block, BK=32, K=256. Grid 8192 blocks. (unchanged from R1)
// ---------------------------------------------------------------------------
__global__ __launch_bounds__(256, 2) void lstm_xz(
    const float* __restrict__ x, const float* __restrict__ w,
    const float* __restrict__ bias, _Float16* __restrict__ xzh)
{
    __shared__ unsigned short Ahi[128 * 40];
    __shared__ unsigned short Alo[128 * 40];
    __shared__ unsigned short Wt [128 * 40];

    const int tid = threadIdx.x;
    int idx = blockIdx.x;
    int xcd = idx & 7;
    int chunk = idx >> 3;
    int msup = chunk >> 7;
    int s = chunk & 127;
    int nt = s >> 3;
    int mi0 = s & 7;
    int mt = xcd * 64 + msup * 8 + mi0;
    const int m0 = mt << 7;
    const int n0 = nt << 7;

    const int lane = tid & 63;
    const int wv = tid >> 6;
    const int wm = wv >> 1, wn = wv & 1;
    const int cB = lane & 15, kgrp = lane >> 4;

    floatx4 acc[4][4];
#pragma unroll
    for (int i = 0; i < 4; ++i)
#pragma unroll
        for (int j = 0; j < 4; ++j) acc[i][j] = (floatx4){0.f, 0.f, 0.f, 0.f};

    float bv[4];
#pragma unroll
    for (int ni = 0; ni < 4; ++ni) bv[ni] = bias[n0 + wn * 64 + ni * 16 + cB];

    for (int it = 0; it < 8; ++it) {
        const int k0 = it * 32;
#pragma unroll
        for (int sw = 0; sw < 4; ++sw) {
            int e = sw * 256 + tid;
            int row = e >> 3, kq = e & 7;
            float4 v = *((const float4*)(x + (size_t)(m0 + row) * Ff + k0) + kq);
            unsigned short h0 = f2bf(v.x), h1 = f2bf(v.y), h2 = f2bf(v.z), h3 = f2bf(v.w);
            unsigned short l0 = f2bf(v.x - bf2f(h0)), l1 = f2bf(v.y - bf2f(h1));
            unsigned short l2 = f2bf(v.z - bf2f(h2)), l3 = f2bf(v.w - bf2f(h3));
            uint2 ph, pl;
            ph.x = (unsigned)h0 | ((unsigned)h1 << 16); ph.y = (unsigned)h2 | ((unsigned)h3 << 16);
            pl.x = (unsigned)l0 | ((unsigned)l1 << 16); pl.y = (unsigned)l2 | ((unsigned)l3 << 16);
            *(uint2*)(&Ahi[row * 40 + kq * 4]) = ph;
            *(uint2*)(&Alo[row * 40 + kq * 4]) = pl;
        }
#pragma unroll
        for (int sw = 0; sw < 4; ++sw) {
            int e = sw * 256 + tid;
            int kr = e >> 5, nq = e & 31;
            float4 v = *((const float4*)(w + (size_t)(k0 + kr) * G4 + n0) + nq);
            int nb = nq * 4;
            Wt[(nb + 0) * 40 + kr] = f2bf(v.x);
            Wt[(nb + 1) * 40 + kr] = f2bf(v.y);
            Wt[(nb + 2) * 40 + kr] = f2bf(v.z);
            Wt[(nb + 3) * 40 + kr] = f2bf(v.w);
        }
        __syncthreads();

        short8 bfr[4];
#pragma unroll
        for (int ni = 0; ni < 4; ++ni)
            bfr[ni] = *(const short8*)(&Wt[(wn * 64 + ni * 16 + cB) * 40 + kgrp * 8]);
#pragma unroll
        for (int mi = 0; mi < 4; ++mi) {
            short8 ah = *(const short8*)(&Ahi[(wm * 64 + mi * 16 + cB) * 40 + kgrp * 8]);
            short8 al = *(const short8*)(&Alo[(wm * 64 + mi * 16 + cB) * 40 + kgrp * 8]);
#pragma unroll
            for (int ni = 0; ni < 4; ++ni) {
                acc[mi][ni] = __builtin_amdgcn_mfma_f32_16x16x32_bf16(ah, bfr[ni], acc[mi][ni], 0, 0, 0);
                acc[mi][ni] = __builtin_amdgcn_mfma_f32_16x16x32_bf16(al, bfr[ni], acc[mi][ni], 0, 0, 0);
            }
        }
        __syncthreads();
    }
#pragma unroll
    for (int mi = 0; mi < 4; ++mi)
#pragma unroll
        for (int ni = 0; ni < 4; ++ni) {
            int rowb = m0 + wm * 64 + mi * 16 + kgrp * 4;
            int col = n0 + wn * 64 + ni * 16 + cB;
#pragma unroll
            for (int rr = 0; rr < 4; ++rr)
                xzh[(size_t)(rowb + rr) * G4 + col] = (_Float16)(acc[mi][ni][rr] + bv[ni]);
        }
}

// ---------------------------------------------------------------------------
// Kernel R: persistent scan, tag-broadcast sync, wave-specialized.
// Grid 512 = 8 row-groups x 64 col-blocks. 256 thr (4 waves: t2 x kh).
// ---------------------------------------------------------------------------
__global__ __launch_bounds__(256, 2) void lstm_rec(
    const _Float16* __restrict__ xzh, const float* __restrict__ rk,
    unsigned* __restrict__ hbuf_u, unsigned* __restrict__ tags,
    float* __restrict__ out)
{
    __shared__ unsigned short Rlds[32 * 520];
    __shared__ unsigned short hlds[16 * 520];
    __shared__ float zbuf[4 * 256];
    __shared__ unsigned xzn[2][256];          // ping-pong next-step xz (512 fp16 each)

    const int tid = threadIdx.x;
    const int idx = blockIdx.x;
    const int rg = idx & 7;
    const int cb = idx >> 3;
    const int b0 = rg * 16;
    const int hc0 = cb * 8;

    const int lane = tid & 63;
    const int wv = tid >> 6;
    const int t2 = wv & 1;
    const int kh = wv >> 1;
    const int cB = lane & 15, kgrp = lane >> 4;

    // preload R slice: Rlds[n][k], n = t2*16+sub, gate = t2*2 + (sub>>3), hcol = sub&7
    for (int e = tid; e < 32 * 512; e += 256) {
        int k = e >> 5, n = e & 31;
        int gate = ((n >> 4) << 1) | ((n >> 3) & 1);
        int col = gate * 512 + hc0 + (n & 7);
        Rlds[n * 520 + k] = f2bf(rk[(size_t)k * G4 + col]);
    }

    unsigned* hb0 = hbuf_u;
    unsigned* hb1 = hbuf_u + (size_t)Bb * Hh / 2;
    unsigned* tagg = tags + rg * 64;          // this group's 64 tags (dense: cheap poll)

    // wave0 elementwise ownership: 64 threads x 2 cells
    const int r = tid >> 2;
    const int cp = tid & 3;
    const int b = b0 + r;
    const bool ew = (tid < 64);
    float creg0 = 0.f, creg1 = 0.f;
    unsigned* hlds_u = (unsigned*)hlds;

    // pre-loop: wave1 prefetch xz(0); waves1-3 stage h(0)=0 from memset'd hb0
    if (wv == 1) {
        const uint4* p = (const uint4*)(xzh + ((size_t)(b0 + (lane >> 2)) * Tt + 0) * G4
                                        + (lane & 3) * 512 + hc0);
        ((uint4*)&xzn[0][0])[lane] = *p;
    }
    if (tid >= 64) {
        const unsigned* hbr = hb0 + (size_t)b0 * 256;
        for (int e = tid - 64; e < 4096; e += 192) {
            unsigned v = __hip_atomic_load(hbr + e, __ATOMIC_RELAXED, __HIP_MEMORY_SCOPE_AGENT);
            hlds_u[(e >> 8) * 260 + (e & 255)] = v;
        }
    }
    __syncthreads();

    for (int t = 0; t < Tt; ++t) {
        // hlds has h(t); xzn[t&1] has xz(t)
        floatx4 acc = (floatx4){0.f, 0.f, 0.f, 0.f};
        {
            const unsigned short* ap = &hlds[cB * 520 + kh * 256 + kgrp * 8];
            const unsigned short* bp = &Rlds[(t2 * 16 + cB) * 520 + kh * 256 + kgrp * 8];
#pragma unroll
            for (int kk = 0; kk < 8; ++kk) {
                short8 a = *(const short8*)(ap + kk * 32);
                short8 bb = *(const short8*)(bp + kk * 32);
                acc = __builtin_amdgcn_mfma_f32_16x16x32_bf16(a, bb, acc, 0, 0, 0);
            }
        }
        {
            float* zp = &zbuf[wv * 256 + kgrp * 64 + cB];  // row=kgrp*4+reg, col=cB
            zp[0]  = acc[0];
            zp[16] = acc[1];
            zp[32] = acc[2];
            zp[48] = acc[3];
        }
        __syncthreads();   // B: zbuf(t) ready

        unsigned* hwr = (t & 1) ? hb0 : hb1;   // h(t+1) buffer
        if (ew) {
            const int base = r * 16;
            const int c0 = 2 * cp, c1 = 2 * cp + 1;
            // xz(t) from LDS ping-pong
            float xzr[8];
#pragma unroll
            for (int g = 0; g < 4; ++g) {
                unsigned v = xzn[t & 1][(r * 4 + g) * 4 + cp];
                xzr[2 * g]     = (float)__builtin_bit_cast(_Float16, (unsigned short)(v & 0xffffu));
                xzr[2 * g + 1] = (float)__builtin_bit_cast(_Float16, (unsigned short)(v >> 16));
            }
            float zi0 = zbuf[base + c0]       + zbuf[512 + base + c0]       + xzr[0];
            float zi1 = zbuf[base + c1]       + zbuf[512 + base + c1]       + xzr[1];
            float zf0 = zbuf[base + 8 + c0]   + zbuf[512 + base + 8 + c0]   + xzr[2];
            float zf1 = zbuf[base + 8 + c1]   + zbuf[512 + base + 8 + c1]   + xzr[3];
            float zg0 = zbuf[256 + base + c0] + zbuf[768 + base + c0]       + xzr[4];
            float zg1 = zbuf[256 + base + c1] + zbuf[768 + base + c1]       + xzr[5];
            float zo0 = zbuf[256 + base + 8 + c0] + zbuf[768 + base + 8 + c0] + xzr[6];
            float zo1 = zbuf[256 + base + 8 + c1] + zbuf[768 + base + 8 + c1] + xzr[7];
            creg0 = sigm(zf0) * creg0 + sigm(zi0) * tanh_f(zg0);
            creg1 = sigm(zf1) * creg1 + sigm(zi1) * tanh_f(zg1);
            float hv0 = sigm(zo0) * tanh_f(creg0);
            float hv1 = sigm(zo1) * tanh_f(creg1);
            // h exchange first: its ack is the only thing gating the tag
            unsigned hp = (unsigned)f2bf(hv0) | ((unsigned)f2bf(hv1) << 16);
            __hip_atomic_store(hwr + (size_t)b * 256 + (hc0 >> 1) + cp, hp,
                               __ATOMIC_RELAXED, __HIP_MEMORY_SCOPE_AGENT);
            if (t < Tt - 1) {
                asm volatile("s_waitcnt vmcnt(0)" ::: "memory");   // h visible at L3
                if (tid == 0)
                    __hip_atomic_store(tagg + cb, (unsigned)(t + 1),
                                       __ATOMIC_RELAXED, __HIP_MEMORY_SCOPE_AGENT);
            }
            // outputs off the critical path
            *(float2*)(out + ((size_t)b * Tt + t) * Hh + hc0 + c0) = make_float2(hv0, hv1);
            if (t == Tt - 1) {
                float* hl = out + (size_t)Bb * Tt * Hh;
                float* cl = hl + (size_t)Bb * Hh;
                *(float2*)(hl + (size_t)b * Hh + hc0 + c0) = make_float2(hv0, hv1);
                *(float2*)(cl + (size_t)b * Hh + hc0 + c0) = make_float2(creg0, creg1);
            }
        } else if (wv == 1 && t < Tt - 1) {
            // prefetch xz(t+1) into the other LDS buffer (overlaps poll + next GEMM)
            const uint4* p = (const uint4*)(xzh + (((size_t)(b0 + (lane >> 2)) * Tt + (t + 1)) * G4)
                                            + (lane & 3) * 512 + hc0);
            ((uint4*)&xzn[(t + 1) & 1][0])[lane] = *p;
        }
        if (t == Tt - 1) break;

        if (tid >= 64) {
            // poll all 64 tags (monotonic): one dword per lane, no RMW chain
            const unsigned tgt = (unsigned)(t + 1);
            while (true) {
                unsigned v = __hip_atomic_load(tagg + lane, __ATOMIC_RELAXED,
                                               __HIP_MEMORY_SCOPE_AGENT);
                if (__all(v >= tgt)) break;
                __builtin_amdgcn_s_sleep(1);
            }
            // stage h(t+1): 4096 dwords over 192 threads
            const unsigned* hbr = hwr + (size_t)b0 * 256;
            for (int e = tid - 64; e < 4096; e += 192) {
                unsigned v = __hip_atomic_load(hbr + e, __ATOMIC_RELAXED,
                                               __HIP_MEMORY_SCOPE_AGENT);
                hlds_u[(e >> 8) * 260 + (e & 255)] = v;
            }
        }
        __syncthreads();   // A: hlds(t+1) + xzn ready
    }
}

// ---------------------------------------------------------------------------
extern "C" void kernel_launch(void* const* d_in, const int* in_sizes, int n_in,
                              void* d_out, int out_size, void* d_ws, size_t ws_size,
                              hipStream_t stream) {
    (void)in_sizes; (void)n_in; (void)out_size; (void)ws_size;
    const float* x    = (const float*)d_in[0];
    const float* w    = (const float*)d_in[1];
    const float* rk   = (const float*)d_in[2];
    const float* bias = (const float*)d_in[3];
    float* out = (float*)d_out;

    char* ws = (char*)d_ws;
    const size_t XZ_BYTES   = (size_t)Bb * Tt * G4 * sizeof(_Float16);      // 268,435,456
    const size_t HBUF_BYTES = (size_t)2 * Bb * Hh * sizeof(unsigned short); // 262,144
    const size_t TAG_BYTES  = 2048;

    _Float16* xzh = (_Float16*)ws;
    unsigned* hbuf = (unsigned*)(ws + XZ_BYTES);
    unsigned* tags = (unsigned*)(ws + XZ_BYTES + HBUF_BYTES);

    hipMemsetAsync(ws + XZ_BYTES, 0, HBUF_BYTES + TAG_BYTES, stream);

    lstm_xz<<<dim3(8192), dim3(256), 0, stream>>>(x, w, bias, xzh);
    lstm_rec<<<dim3(512), dim3(256), 0, stream>>>(xzh, rk, hbuf, tags, out);
}

// Round 4
// 5054.071 us; speedup vs baseline: 1.4072x; 1.4072x over previous
//
#include <hip/hip_runtime.h>
#include <stdint.h>

// LSTM forward, B=128 T=512 F=256 H=512, Keras gate order i,f,g,o.
//  kernel lstm_xz : xz[B*T,2048] = x @ kernel + bias  (split-bf16 MFMA, fp16 output in ws)
//  kernel lstm_rec: persistent scan. 8 row groups (16 rows) x 64 col-blocks (8 h-cols).
//    R4: tag-broadcast with 128-B padded tags (one L3 line per block -> parallel
//    stores, no line contention; R3's packed tags serialized behind a read storm).
//    xz prefetch issued at loop top (overlaps GEMM+sync), ds_write after sync B,
//    so poll vmcnt never drains an HBM load. Fence-free sc1 protocol throughout.
// ws layout: [0, 256MB) xz fp16 | hbuf 2x128x512 bf16 (256KB) | tags 64KB (padded)

#define Bb 128
#define Tt 512
#define Ff 256
#define Hh 512
#define G4 2048

typedef __attribute__((ext_vector_type(8))) short short8;
typedef __attribute__((ext_vector_type(4))) float floatx4;

__device__ __forceinline__ unsigned short f2bf(float f) {
    unsigned u = __float_as_uint(f);
    return (unsigned short)((u + 0x7FFFu + ((u >> 16) & 1u)) >> 16);
}
__device__ __forceinline__ float bf2f(unsigned short h) {
    return __uint_as_float(((unsigned)h) << 16);
}
__device__ __forceinline__ float sigm(float x) { return 1.f / (1.f + __expf(-x)); }
__device__ __forceinline__ float tanh_f(float x) {
    float e = __expf(-2.f * fabsf(x));
    return copysignf((1.f - e) / (1.f + e), x);
}

// ---------------------------------------------------------------------------
// Kernel A: xz = x @ w + bias, stored fp16. Split-bf16 (x=hi+lo) for accuracy.
// 128x128 tile / block, BK=32, K=256. Grid 8192 blocks. (unchanged)
// ---------------------------------------------------------------------------
__global__ __launch_bounds__(256, 2) void lstm_xz(
    const float* __restrict__ x, const float* __restrict__ w,
    const float* __restrict__ bias, _Float16* __restrict__ xzh)
{
    __shared__ unsigned short Ahi[128 * 40];
    __shared__ unsigned short Alo[128 * 40];
    __shared__ unsigned short Wt [128 * 40];

    const int tid = threadIdx.x;
    int idx = blockIdx.x;
    int xcd = idx & 7;
    int chunk = idx >> 3;
    int msup = chunk >> 7;
    int s = chunk & 127;
    int nt = s >> 3;
    int mi0 = s & 7;
    int mt = xcd * 64 + msup * 8 + mi0;
    const int m0 = mt << 7;
    const int n0 = nt << 7;

    const int lane = tid & 63;
    const int wv = tid >> 6;
    const int wm = wv >> 1, wn = wv & 1;
    const int cB = lane & 15, kgrp = lane >> 4;

    floatx4 acc[4][4];
#pragma unroll
    for (int i = 0; i < 4; ++i)
#pragma unroll
        for (int j = 0; j < 4; ++j) acc[i][j] = (floatx4){0.f, 0.f, 0.f, 0.f};

    float bv[4];
#pragma unroll
    for (int ni = 0; ni < 4; ++ni) bv[ni] = bias[n0 + wn * 64 + ni * 16 + cB];

    for (int it = 0; it < 8; ++it) {
        const int k0 = it * 32;
#pragma unroll
        for (int sw = 0; sw < 4; ++sw) {
            int e = sw * 256 + tid;
            int row = e >> 3, kq = e & 7;
            float4 v = *((const float4*)(x + (size_t)(m0 + row) * Ff + k0) + kq);
            unsigned short h0 = f2bf(v.x), h1 = f2bf(v.y), h2 = f2bf(v.z), h3 = f2bf(v.w);
            unsigned short l0 = f2bf(v.x - bf2f(h0)), l1 = f2bf(v.y - bf2f(h1));
            unsigned short l2 = f2bf(v.z - bf2f(h2)), l3 = f2bf(v.w - bf2f(h3));
            uint2 ph, pl;
            ph.x = (unsigned)h0 | ((unsigned)h1 << 16); ph.y = (unsigned)h2 | ((unsigned)h3 << 16);
            pl.x = (unsigned)l0 | ((unsigned)l1 << 16); pl.y = (unsigned)l2 | ((unsigned)l3 << 16);
            *(uint2*)(&Ahi[row * 40 + kq * 4]) = ph;
            *(uint2*)(&Alo[row * 40 + kq * 4]) = pl;
        }
#pragma unroll
        for (int sw = 0; sw < 4; ++sw) {
            int e = sw * 256 + tid;
            int kr = e >> 5, nq = e & 31;
            float4 v = *((const float4*)(w + (size_t)(k0 + kr) * G4 + n0) + nq);
            int nb = nq * 4;
            Wt[(nb + 0) * 40 + kr] = f2bf(v.x);
            Wt[(nb + 1) * 40 + kr] = f2bf(v.y);
            Wt[(nb + 2) * 40 + kr] = f2bf(v.z);
            Wt[(nb + 3) * 40 + kr] = f2bf(v.w);
        }
        __syncthreads();

        short8 bfr[4];
#pragma unroll
        for (int ni = 0; ni < 4; ++ni)
            bfr[ni] = *(const short8*)(&Wt[(wn * 64 + ni * 16 + cB) * 40 + kgrp * 8]);
#pragma unroll
        for (int mi = 0; mi < 4; ++mi) {
            short8 ah = *(const short8*)(&Ahi[(wm * 64 + mi * 16 + cB) * 40 + kgrp * 8]);
            short8 al = *(const short8*)(&Alo[(wm * 64 + mi * 16 + cB) * 40 + kgrp * 8]);
#pragma unroll
            for (int ni = 0; ni < 4; ++ni) {
                acc[mi][ni] = __builtin_amdgcn_mfma_f32_16x16x32_bf16(ah, bfr[ni], acc[mi][ni], 0, 0, 0);
                acc[mi][ni] = __builtin_amdgcn_mfma_f32_16x16x32_bf16(al, bfr[ni], acc[mi][ni], 0, 0, 0);
            }
        }
        __syncthreads();
    }
#pragma unroll
    for (int mi = 0; mi < 4; ++mi)
#pragma unroll
        for (int ni = 0; ni < 4; ++ni) {
            int rowb = m0 + wm * 64 + mi * 16 + kgrp * 4;
            int col = n0 + wn * 64 + ni * 16 + cB;
#pragma unroll
            for (int rr = 0; rr < 4; ++rr)
                xzh[(size_t)(rowb + rr) * G4 + col] = (_Float16)(acc[mi][ni][rr] + bv[ni]);
        }
}

// ---------------------------------------------------------------------------
// Kernel R: persistent scan, padded-tag sync, wave-specialized.
// Grid 512 = 8 row-groups x 64 col-blocks. 256 thr (4 waves: t2 x kh).
// Tag slot for block (rg,cb): tags[(rg*64+cb)*32]  (128-B stride, own L3 line).
// ---------------------------------------------------------------------------
__global__ __launch_bounds__(256, 2) void lstm_rec(
    const _Float16* __restrict__ xzh, const float* __restrict__ rk,
    unsigned* __restrict__ hbuf_u, unsigned* __restrict__ tags,
    float* __restrict__ out)
{
    __shared__ unsigned short Rlds[32 * 520];
    __shared__ unsigned short hlds[16 * 520];
    __shared__ float zbuf[4 * 256];
    __shared__ unsigned xzn[2][256];          // ping-pong next-step xz (512 fp16 each)

    const int tid = threadIdx.x;
    const int idx = blockIdx.x;
    const int rg = idx & 7;
    const int cb = idx >> 3;
    const int b0 = rg * 16;
    const int hc0 = cb * 8;

    const int lane = tid & 63;
    const int wv = tid >> 6;
    const int t2 = wv & 1;
    const int kh = wv >> 1;
    const int cB = lane & 15, kgrp = lane >> 4;

    // preload R slice: Rlds[n][k], n = t2*16+sub, gate = t2*2 + (sub>>3), hcol = sub&7
    for (int e = tid; e < 32 * 512; e += 256) {
        int k = e >> 5, n = e & 31;
        int gate = ((n >> 4) << 1) | ((n >> 3) & 1);
        int col = gate * 512 + hc0 + (n & 7);
        Rlds[n * 520 + k] = f2bf(rk[(size_t)k * G4 + col]);
    }

    unsigned* hb0 = hbuf_u;
    unsigned* hb1 = hbuf_u + (size_t)Bb * Hh / 2;
    unsigned* tagg = tags + rg * 64 * 32;     // this group's 64 padded tag slots

    // wave0 elementwise ownership: 64 threads x 2 cells
    const int r = tid >> 2;
    const int cp = tid & 3;
    const int b = b0 + r;
    const bool ew = (tid < 64);
    float creg0 = 0.f, creg1 = 0.f;
    unsigned* hlds_u = (unsigned*)hlds;

    // pre-loop: wave1 prefetch xz(0); waves1-3 stage h(0)=0 from memset'd hb0
    if (wv == 1) {
        const uint4* p = (const uint4*)(xzh + ((size_t)(b0 + (lane >> 2)) * Tt + 0) * G4
                                        + (lane & 3) * 512 + hc0);
        ((uint4*)&xzn[0][0])[lane] = *p;
    }
    if (tid >= 64) {
        const unsigned* hbr = hb0 + (size_t)b0 * 256;
        for (int e = tid - 64; e < 4096; e += 192) {
            unsigned v = __hip_atomic_load(hbr + e, __ATOMIC_RELAXED, __HIP_MEMORY_SCOPE_AGENT);
            hlds_u[(e >> 8) * 260 + (e & 255)] = v;
        }
    }
    __syncthreads();

    for (int t = 0; t < Tt; ++t) {
        // wave1: ISSUE xz(t+1) loads now — consumed (ds_write) only after sync B,
        // so the HBM latency overlaps GEMM + zbuf sync and never gates the poll.
        uint4 xzpf;
        if (wv == 1 && t < Tt - 1) {
            xzpf = *(const uint4*)(xzh + (((size_t)(b0 + (lane >> 2)) * Tt + (t + 1)) * G4)
                                   + (lane & 3) * 512 + hc0);
        }

        // hlds has h(t); xzn[t&1] has xz(t)
        floatx4 acc = (floatx4){0.f, 0.f, 0.f, 0.f};
        {
            const unsigned short* ap = &hlds[cB * 520 + kh * 256 + kgrp * 8];
            const unsigned short* bp = &Rlds[(t2 * 16 + cB) * 520 + kh * 256 + kgrp * 8];
#pragma unroll
            for (int kk = 0; kk < 8; ++kk) {
                short8 a = *(const short8*)(ap + kk * 32);
                short8 bb = *(const short8*)(bp + kk * 32);
                acc = __builtin_amdgcn_mfma_f32_16x16x32_bf16(a, bb, acc, 0, 0, 0);
            }
        }
        {
            float* zp = &zbuf[wv * 256 + kgrp * 64 + cB];  // row=kgrp*4+reg, col=cB
            zp[0]  = acc[0];
            zp[16] = acc[1];
            zp[32] = acc[2];
            zp[48] = acc[3];
        }
        __syncthreads();   // B: zbuf(t) ready

        unsigned* hwr = (t & 1) ? hb0 : hb1;   // h(t+1) buffer
        if (ew) {
            const int base = r * 16;
            const int c0 = 2 * cp, c1 = 2 * cp + 1;
            float xzr[8];
#pragma unroll
            for (int g = 0; g < 4; ++g) {
                unsigned v = xzn[t & 1][(r * 4 + g) * 4 + cp];
                xzr[2 * g]     = (float)__builtin_bit_cast(_Float16, (unsigned short)(v & 0xffffu));
                xzr[2 * g + 1] = (float)__builtin_bit_cast(_Float16, (unsigned short)(v >> 16));
            }
            float zi0 = zbuf[base + c0]       + zbuf[512 + base + c0]       + xzr[0];
            float zi1 = zbuf[base + c1]       + zbuf[512 + base + c1]       + xzr[1];
            float zf0 = zbuf[base + 8 + c0]   + zbuf[512 + base + 8 + c0]   + xzr[2];
            float zf1 = zbuf[base + 8 + c1]   + zbuf[512 + base + 8 + c1]   + xzr[3];
            float zg0 = zbuf[256 + base + c0] + zbuf[768 + base + c0]       + xzr[4];
            float zg1 = zbuf[256 + base + c1] + zbuf[768 + base + c1]       + xzr[5];
            float zo0 = zbuf[256 + base + 8 + c0] + zbuf[768 + base + 8 + c0] + xzr[6];
            float zo1 = zbuf[256 + base + 8 + c1] + zbuf[768 + base + 8 + c1] + xzr[7];
            creg0 = sigm(zf0) * creg0 + sigm(zi0) * tanh_f(zg0);
            creg1 = sigm(zf1) * creg1 + sigm(zi1) * tanh_f(zg1);
            float hv0 = sigm(zo0) * tanh_f(creg0);
            float hv1 = sigm(zo1) * tanh_f(creg1);
            // h exchange first: its ack is the only thing gating the tag
            unsigned hp = (unsigned)f2bf(hv0) | ((unsigned)f2bf(hv1) << 16);
            __hip_atomic_store(hwr + (size_t)b * 256 + (hc0 >> 1) + cp, hp,
                               __ATOMIC_RELAXED, __HIP_MEMORY_SCOPE_AGENT);
            if (t < Tt - 1) {
                asm volatile("s_waitcnt vmcnt(0)" ::: "memory");   // h visible at L3
                if (tid == 0)
                    __hip_atomic_store(tagg + cb * 32, (unsigned)(t + 1),
                                       __ATOMIC_RELAXED, __HIP_MEMORY_SCOPE_AGENT);
            }
            // outputs off the critical path
            *(float2*)(out + ((size_t)b * Tt + t) * Hh + hc0 + c0) = make_float2(hv0, hv1);
            if (t == Tt - 1) {
                float* hl = out + (size_t)Bb * Tt * Hh;
                float* cl = hl + (size_t)Bb * Hh;
                *(float2*)(hl + (size_t)b * Hh + hc0 + c0) = make_float2(hv0, hv1);
                *(float2*)(cl + (size_t)b * Hh + hc0 + c0) = make_float2(creg0, creg1);
            }
        } else if (wv == 1 && t < Tt - 1) {
            // commit prefetched xz(t+1) to LDS ping-pong (load issued at loop top)
            ((uint4*)&xzn[(t + 1) & 1][0])[lane] = xzpf;
        }
        if (t == Tt - 1) break;

        if (tid >= 64) {
            // poll all 64 padded tags: lane l reads block l's own 128-B line.
            // Distinct lines -> stores and polls never queue on the same bank entry.
            const unsigned tgt = (unsigned)(t + 1);
            while (true) {
                unsigned v = __hip_atomic_load(tagg + lane * 32, __ATOMIC_RELAXED,
                                               __HIP_MEMORY_SCOPE_AGENT);
                if (__all(v >= tgt)) break;
                __builtin_amdgcn_s_sleep(1);
            }
            // stage h(t+1): 4096 dwords over 192 threads
            const unsigned* hbr = hwr + (size_t)b0 * 256;
            for (int e = tid - 64; e < 4096; e += 192) {
                unsigned v = __hip_atomic_load(hbr + e, __ATOMIC_RELAXED,
                                               __HIP_MEMORY_SCOPE_AGENT);
                hlds_u[(e >> 8) * 260 + (e & 255)] = v;
            }
        }
        __syncthreads();   // A: hlds(t+1) + xzn ready
    }
}

// ---------------------------------------------------------------------------
extern "C" void kernel_launch(void* const* d_in, const int* in_sizes, int n_in,
                              void* d_out, int out_size, void* d_ws, size_t ws_size,
                              hipStream_t stream) {
    (void)in_sizes; (void)n_in; (void)out_size; (void)ws_size;
    const float* x    = (const float*)d_in[0];
    const float* w    = (const float*)d_in[1];
    const float* rk   = (const float*)d_in[2];
    const float* bias = (const float*)d_in[3];
    float* out = (float*)d_out;

    char* ws = (char*)d_ws;
    const size_t XZ_BYTES   = (size_t)Bb * Tt * G4 * sizeof(_Float16);      // 268,435,456
    const size_t HBUF_BYTES = (size_t)2 * Bb * Hh * sizeof(unsigned short); // 262,144
    const size_t TAG_BYTES  = 8 * 64 * 128;                                 // 65,536 (padded)

    _Float16* xzh = (_Float16*)ws;
    unsigned* hbuf = (unsigned*)(ws + XZ_BYTES);
    unsigned* tags = (unsigned*)(ws + XZ_BYTES + HBUF_BYTES);

    hipMemsetAsync(ws + XZ_BYTES, 0, HBUF_BYTES + TAG_BYTES, stream);

    lstm_xz<<<dim3(8192), dim3(256), 0, stream>>>(x, w, bias, xzh);
    lstm_rec<<<dim3(512), dim3(256), 0, stream>>>(xzh, rk, hbuf, tags, out);
}